// Round 14
// baseline (51.405 us; speedup 1.0000x reference)
//
#include <hip/hip_runtime.h>
#include <math.h>
#include <stdint.h>

#define NHEAD 4
#define DD 100
#define NW 39            // word rows
#define BLOCK 256

typedef float v2f __attribute__((ext_vector_type(2)));
typedef __attribute__((address_space(3))) uint32_t lds_t;
typedef const __attribute__((address_space(1))) uint32_t glb_t;

__global__ __launch_bounds__(BLOCK, 8) void ts_enc(
    const float* __restrict__ x,       // [4800][40][100]
    const float* __restrict__ w_att,   // [4][100]
    const float* __restrict__ b_att,   // [4][100]
    float* __restrict__ out)           // [4800][400]
{
    __shared__ float tile[40 * DD];      // 16000 B: row0 = type_emb, rows 1..39 = words
    __shared__ float scp[NHEAD][4][40];  // [head][wave-partial][n] — conflict-free b32

    const int tid  = threadIdx.x;
    const int wv   = __builtin_amdgcn_readfirstlane(tid >> 6);
    const int lane = tid & 63;
    const float* xsite = x + (size_t)blockIdx.x * (40 * DD);

    // ---- stage site tile: async global->LDS, 16 B/lane, 1000 float4 chunks ----
    #pragma unroll
    for (int i = 0; i < 4; ++i) {
        const int cf = i * BLOCK + tid;
        if (cf < 1000) {
            glb_t* g = (glb_t*)(xsite + cf * 4);
            lds_t* l = (lds_t*)(tile + (i * BLOCK + wv * 64) * 4);
            __builtin_amdgcn_global_load_lds(g, l, 16, 0, 0);
        }
    }
    __syncthreads();                                   // barrier 1: tile ready

    // ---- Phase A: d-split (wave wv owns chunks wv*6..wv*6+5, wave0 +24);
    //      lane = n; slab-batched uniform s_loads; packed math ----
    // leaky(p) = max(p, 0.3p)
    const bool act  = lane < NW;
    const int  nrow = act ? lane : NW - 1;             // clamp idle lanes
    const float* wrow = tile + (1 + nrow) * DD;

    v2f accA[NHEAD] = {{0,0},{0,0},{0,0},{0,0}};
    v2f accB[NHEAD] = {{0,0},{0,0},{0,0},{0,0}};

#define CBODY(c_, h_, w4, b4) { \
        const v2f w01 = {w4.x, w4.y}, w23 = {w4.z, w4.w}; \
        const v2f b01 = {b4.x, b4.y}, b23 = {b4.z, b4.w}; \
        const v2f p01 = x01 * w01 + b01; \
        const v2f p23 = x23 * w23 + b23; \
        const v2f l01 = __builtin_elementwise_max(p01, 0.3f * p01); \
        const v2f l23 = __builtin_elementwise_max(p23, 0.3f * p23); \
        accA[h_] = t01 * l01 + accA[h_]; \
        accB[h_] = t23 * l23 + accB[h_]; }

    #pragma unroll
    for (int hp = 0; hp < 2; ++hp) {                   // head pair
        #pragma unroll
        for (int jh = 0; jh < 2; ++jh) {               // 3-chunk half
            // ---- slab: 12 uniform float4 loads -> batched s_load_dwordx4 ----
            float4 ws0[3], ws1[3], bs0[3], bs1[3];
            #pragma unroll
            for (int j = 0; j < 3; ++j) {
                const int c_ = wv * 6 + jh * 3 + j;
                ws0[j] = *(const float4*)(w_att + (2 * hp    ) * DD + c_ * 4);
                ws1[j] = *(const float4*)(w_att + (2 * hp + 1) * DD + c_ * 4);
                bs0[j] = *(const float4*)(b_att + (2 * hp    ) * DD + c_ * 4);
                bs1[j] = *(const float4*)(b_att + (2 * hp + 1) * DD + c_ * 4);
            }
            #pragma unroll
            for (int j = 0; j < 3; ++j) {
                const int c_ = wv * 6 + jh * 3 + j;
                const v2f x01 = *(const v2f*)(wrow + c_ * 4);      // ds_read
                const v2f x23 = *(const v2f*)(wrow + c_ * 4 + 2);
                const v2f t01 = *(const v2f*)(xsite + c_ * 4);     // uniform s_load
                const v2f t23 = *(const v2f*)(xsite + c_ * 4 + 2);
                CBODY(c_, 2 * hp,     ws0[j], bs0[j])
                CBODY(c_, 2 * hp + 1, ws1[j], bs1[j])
            }
        }
    }
    if (wv == 0) {                                     // tail chunk 24 (uniform branch)
        const int c_ = 24;
        const v2f x01 = *(const v2f*)(wrow + c_ * 4);
        const v2f x23 = *(const v2f*)(wrow + c_ * 4 + 2);
        const v2f t01 = *(const v2f*)(xsite + c_ * 4);
        const v2f t23 = *(const v2f*)(xsite + c_ * 4 + 2);
        #pragma unroll
        for (int h = 0; h < NHEAD; ++h) {
            const float4 w4 = *(const float4*)(w_att + h * DD + c_ * 4);
            const float4 b4 = *(const float4*)(b_att + h * DD + c_ * 4);
            CBODY(c_, h, w4, b4)
        }
    }
#undef CBODY

    if (act) {
        #pragma unroll
        for (int h = 0; h < NHEAD; ++h)
            scp[h][wv][lane] = (accA[h].x + accA[h].y) + (accB[h].x + accB[h].y);
    }
    __syncthreads();                                   // barrier 2: scp ready

    // ---- Phase B: wave wv = head wv; raw exp (reference math); NO shuffles ----
    float sc = 0.f;
    if (act) sc = (scp[wv][0][lane] + scp[wv][1][lane])
                + (scp[wv][2][lane] + scp[wv][3][lane]);
    const float e = act ? __expf(sc) : 0.f;            // lane n holds e[head=wv][n]

    // ---- Phase C: wave = head, lane = d-pair (50 active); att via v_readlane;
    //      denominator folded into the same loop; normalize at store ----
    const int l2 = lane < 50 ? lane : 49;
    const float* wb = tile + DD + l2 * 2;
    v2f o = {0.f, 0.f};
    float s = 0.f;
    #pragma unroll
    for (int n = 0; n < NW; ++n) {
        const float en = __builtin_bit_cast(float,
            __builtin_amdgcn_readlane(__builtin_bit_cast(int, e), n));
        const v2f wd = *(const v2f*)(wb + n * DD);     // 50-lane b64
        o = en * wd + o;                               // v_pk_fma, SGPR broadcast
        s += en;                                       // scalar add (same SGPR)
    }
    const float r = 1.f / s;                           // all-zero site: s=39, o=0 ✓
    if (lane < 50) {
        const v2f q = o * r;
        *(v2f*)(out + (size_t)blockIdx.x * (NHEAD * DD) + wv * DD + lane * 2) = q;
    }
}

extern "C" void kernel_launch(void* const* d_in, const int* in_sizes, int n_in,
                              void* d_out, int out_size, void* d_ws, size_t ws_size,
                              hipStream_t stream) {
    const float* x     = (const float*)d_in[0];
    const float* w_att = (const float*)d_in[1];
    const float* b_att = (const float*)d_in[2];
    float* out = (float*)d_out;

    const int sites = 8 * 30 * 20;   // 4800
    ts_enc<<<sites, BLOCK, 0, stream>>>(x, w_att, b_att, out);
}

// Round 15
// 38.294 us; speedup vs baseline: 1.3424x; 1.3424x over previous
//
#include <hip/hip_runtime.h>
#include <math.h>
#include <stdint.h>

#define NHEAD 4
#define DD 100
#define NW 39            // word rows
#define BLOCK 128        // 2 waves; wave w owns heads 2w, 2w+1 END-TO-END
#define RW 54            // u32 words per LDS row (216 B: 8B-aligned, stride 22 mod 32)

typedef float v2f __attribute__((ext_vector_type(2)));

__global__ __launch_bounds__(BLOCK, 8) void ts_enc(
    const float* __restrict__ x,       // [4800][40][100]
    const float* __restrict__ w_att,   // [4][100]
    const float* __restrict__ b_att,   // [4][100]
    float* __restrict__ out)           // [4800][400]
{
    __shared__ uint32_t wl[NW * RW];   // words rows 1..39 as packed bf16 pairs (8.4 KB)

    const int tid  = threadIdx.x;
    const int wv   = __builtin_amdgcn_readfirstlane(tid >> 6);   // 0,1
    const int lane = tid & 63;
    const float* xsite = x + (size_t)blockIdx.x * (40 * DD);

    // ---- stage words (rows 1..39) as bf16: f32x4 load -> cvt_pk RNE -> b64 write ----
    #pragma unroll
    for (int i = 0; i < 8; ++i) {
        const int f = i * BLOCK + tid;              // words-chunk 0..974
        if (f < 975) {
            const float4 q = *(const float4*)(xsite + DD + f * 4);
            const int r = f / 25;                   // word row 0..38
            const int m = f - r * 25;               // chunk in row
            uint32_t p0, p1;                        // pack: low16 = bf16(src0)
            asm("v_cvt_pk_bf16_f32 %0, %1, %2" : "=v"(p0) : "v"(q.x), "v"(q.y));
            asm("v_cvt_pk_bf16_f32 %0, %1, %2" : "=v"(p1) : "v"(q.z), "v"(q.w));
            *(uint2*)&wl[r * RW + m * 2] = make_uint2(p0, p1);
        }
    }
    __syncthreads();                                // the ONLY barrier

    // ---- Phase A: lane = n; this wave's 2 heads, all 25 chunks in-wave ----
    // leaky(p) = max(p, 0.3p); te/w/b wave-uniform -> scalar pipe
    const bool act  = lane < NW;
    const int  nrow = act ? lane : NW - 1;
    const uint32_t* wr = wl + nrow * RW;
    const int h0 = 2 * wv;

    v2f ac0A = {0,0}, ac0B = {0,0}, ac1A = {0,0}, ac1B = {0,0};

    #pragma unroll
    for (int c = 0; c < 25; ++c) {
        const uint2 v = *(const uint2*)(wr + c * 2);           // 4 bf16 d-elems
        const v2f x01 = { __builtin_bit_cast(float, v.x << 16),
                          __builtin_bit_cast(float, v.x & 0xFFFF0000u) };
        const v2f x23 = { __builtin_bit_cast(float, v.y << 16),
                          __builtin_bit_cast(float, v.y & 0xFFFF0000u) };
        const v2f t01 = *(const v2f*)(xsite + c * 4);          // uniform s_load
        const v2f t23 = *(const v2f*)(xsite + c * 4 + 2);
        #pragma unroll
        for (int hh = 0; hh < 2; ++hh) {
            const int h = h0 + hh;
            const v2f w01 = *(const v2f*)(w_att + h * DD + c * 4);
            const v2f w23 = *(const v2f*)(w_att + h * DD + c * 4 + 2);
            const v2f b01 = *(const v2f*)(b_att + h * DD + c * 4);
            const v2f b23 = *(const v2f*)(b_att + h * DD + c * 4 + 2);
            const v2f p01 = x01 * w01 + b01;
            const v2f p23 = x23 * w23 + b23;
            const v2f l01 = __builtin_elementwise_max(p01, 0.3f * p01);
            const v2f l23 = __builtin_elementwise_max(p23, 0.3f * p23);
            if (hh == 0) { ac0A = t01 * l01 + ac0A; ac0B = t23 * l23 + ac0B; }
            else         { ac1A = t01 * l01 + ac1A; ac1B = t23 * l23 + ac1B; }
        }
    }
    const float sc0 = (ac0A.x + ac0A.y) + (ac0B.x + ac0B.y);
    const float sc1 = (ac1A.x + ac1A.y) + (ac1B.x + ac1B.y);

    // ---- Phase B: raw exp (reference math) + 6-stage sum tree; att in-lane ----
    const float e0 = act ? __expf(sc0) : 0.f;
    const float e1 = act ? __expf(sc1) : 0.f;
    float sm0 = e0, sm1 = e1;
    #pragma unroll
    for (int off = 32; off; off >>= 1) {
        sm0 += __shfl_xor(sm0, off);
        sm1 += __shfl_xor(sm1, off);
    }
    const float att0 = e0 * __builtin_amdgcn_rcpf(sm0);   // lane n holds att[h0][n]
    const float att1 = e1 * __builtin_amdgcn_rcpf(sm1);

    // ---- Phase C: lane = d-pair (50 active); 1 b32 read per n serves both heads;
    //      att via v_readlane (SGPR feeds v_pk_fma) ----
    const int l2 = lane < 50 ? lane : 49;
    const uint32_t* cb = wl + l2;
    v2f o0 = {0,0}, o1 = {0,0};
    #pragma unroll
    for (int n = 0; n < NW; ++n) {
        const uint32_t u = cb[n * RW];                      // 50 consec words, ≤2-way
        const v2f wd = { __builtin_bit_cast(float, u << 16),
                         __builtin_bit_cast(float, u & 0xFFFF0000u) };
        const float a0 = __builtin_bit_cast(float,
            __builtin_amdgcn_readlane(__builtin_bit_cast(int, att0), n));
        const float a1 = __builtin_bit_cast(float,
            __builtin_amdgcn_readlane(__builtin_bit_cast(int, att1), n));
        o0 = a0 * wd + o0;
        o1 = a1 * wd + o1;
    }
    if (lane < 50) {
        float* ob = out + (size_t)blockIdx.x * (NHEAD * DD) + h0 * DD + lane * 2;
        *(v2f*)(ob)      = o0;
        *(v2f*)(ob + DD) = o1;
    }
}

extern "C" void kernel_launch(void* const* d_in, const int* in_sizes, int n_in,
                              void* d_out, int out_size, void* d_ws, size_t ws_size,
                              hipStream_t stream) {
    const float* x     = (const float*)d_in[0];
    const float* w_att = (const float*)d_in[1];
    const float* b_att = (const float*)d_in[2];
    float* out = (float*)d_out;

    const int sites = 8 * 30 * 20;   // 4800
    ts_enc<<<sites, BLOCK, 0, stream>>>(x, w_att, b_att, out);
}